// Round 1
// baseline (1080.484 us; speedup 1.0000x reference)
//
#include <hip/hip_runtime.h>

#define B 8
#define H 1024
#define W 1024
#define NPIX (H * W)          // 1048576 per image
#define TOPK 4096
#define NBUCK 32512           // 0x3F800000 >> 15
#define HSTRIDE 32768
#define CANDCAP 131072        // per image, >= theoretical max 116964
#define GCAP 8192             // gathered per image

// ---------------- NMS passes ----------------

// m0 = (s == maxpool5x5(s))
__global__ void k_m0(const float* __restrict__ S, unsigned char* __restrict__ m0) {
    int idx = blockIdx.x * 256 + threadIdx.x;        // < B*NPIX
    int rem = idx & (NPIX - 1);
    int y = rem >> 10, x = rem & (W - 1);
    const float* Sb = S + (size_t)(idx - rem);
    float c = Sb[rem];
    float mx = c;
#pragma unroll
    for (int dy = -2; dy <= 2; ++dy) {
        int yy = y + dy;
        if (yy < 0 || yy >= H) continue;
#pragma unroll
        for (int dx = -2; dx <= 2; ++dx) {
            int xx = x + dx;
            if (xx < 0 || xx >= W) continue;
            float v = Sb[(yy << 10) + xx];
            mx = fmaxf(mx, v);
        }
    }
    m0[idx] = (c == mx) ? 1 : 0;
}

// sp = dilate5x5(mIn) ; ss = sp ? 0 : s
__global__ void k_dilate_ss(const unsigned char* __restrict__ mIn,
                            const float* __restrict__ S,
                            unsigned char* __restrict__ spOut,
                            float* __restrict__ ssOut) {
    int idx = blockIdx.x * 256 + threadIdx.x;
    int rem = idx & (NPIX - 1);
    int y = rem >> 10, x = rem & (W - 1);
    const unsigned char* mb = mIn + (size_t)(idx - rem);
    int acc = 0;
#pragma unroll
    for (int dy = -2; dy <= 2; ++dy) {
        int yy = y + dy;
        if (yy < 0 || yy >= H) continue;
#pragma unroll
        for (int dx = -2; dx <= 2; ++dx) {
            int xx = x + dx;
            if (xx < 0 || xx >= W) continue;
            acc |= mb[(yy << 10) + xx];
        }
    }
    spOut[idx] = acc ? 1 : 0;
    ssOut[idx] = acc ? 0.0f : S[idx];
}

// new = (ss == maxpool5x5(ss)); mOut = mPrev | (new & ~sp)
__global__ void k_newmask(const float* __restrict__ ss,
                          const unsigned char* __restrict__ mPrev,
                          const unsigned char* __restrict__ sp,
                          unsigned char* __restrict__ mOut) {
    int idx = blockIdx.x * 256 + threadIdx.x;
    int rem = idx & (NPIX - 1);
    int y = rem >> 10, x = rem & (W - 1);
    const float* sb = ss + (size_t)(idx - rem);
    float c = sb[rem];
    float mx = c;
#pragma unroll
    for (int dy = -2; dy <= 2; ++dy) {
        int yy = y + dy;
        if (yy < 0 || yy >= H) continue;
#pragma unroll
        for (int dx = -2; dx <= 2; ++dx) {
            int xx = x + dx;
            if (xx < 0 || xx >= W) continue;
            mx = fmaxf(mx, sb[(yy << 10) + xx]);
        }
    }
    bool nw = (c == mx);
    mOut[idx] = ((mPrev[idx] != 0) || (nw && sp[idx] == 0)) ? 1 : 0;
}

// final: new2, m2, nms value, border zero, compact candidates + histogram
__global__ void k_final_nms(const float* __restrict__ S,
                            const float* __restrict__ ss,
                            const unsigned char* __restrict__ m1,
                            const unsigned char* __restrict__ sp,
                            unsigned long long* __restrict__ cand,
                            unsigned int* __restrict__ cnt,
                            unsigned int* __restrict__ hist) {
    __shared__ unsigned int lcnt;
    __shared__ unsigned int lbase;
    __shared__ unsigned long long lbuf[1024];
    if (threadIdx.x == 0) lcnt = 0;
    __syncthreads();
    int img = blockIdx.x >> 9;                 // 512 blocks per image
    size_t base = (size_t)blockIdx.x * 2048;   // 8 px/thread
    for (int k2 = 0; k2 < 8; ++k2) {
        int idx = (int)base + k2 * 256 + threadIdx.x;
        int rem = idx & (NPIX - 1);
        int y = rem >> 10, x = rem & (W - 1);
        const float* sb = ss + (size_t)(idx - rem);
        float c = sb[rem];
        float mx = c;
#pragma unroll
        for (int dy = -2; dy <= 2; ++dy) {
            int yy = y + dy;
            if (yy < 0 || yy >= H) continue;
#pragma unroll
            for (int dx = -2; dx <= 2; ++dx) {
                int xx = x + dx;
                if (xx < 0 || xx >= W) continue;
                mx = fmaxf(mx, sb[(yy << 10) + xx]);
            }
        }
        bool nw = (c == mx);
        bool m2 = (m1[idx] != 0) || (nw && sp[idx] == 0);
        float val = m2 ? S[idx] : 0.0f;
        if (y < 2 || y > H - 3 || x < 2 || x > W - 3) val = 0.0f;
        if (val > 0.0f) {
            unsigned vb = __float_as_uint(val);
            unsigned bucket = vb >> 15;
            if (bucket > NBUCK - 1) bucket = NBUCK - 1;
            atomicAdd(&hist[((unsigned)img << 15) + bucket], 1u);
            unsigned p = atomicAdd(&lcnt, 1u);
            if (p < 1024)
                lbuf[p] = ((unsigned long long)vb << 32) | (unsigned)(~(unsigned)rem);
        }
    }
    __syncthreads();
    if (threadIdx.x == 0) lbase = atomicAdd(&cnt[img], lcnt);
    __syncthreads();
    unsigned n = lcnt;
    for (unsigned i = threadIdx.x; i < n; i += 256)
        cand[((size_t)img << 17) + lbase + i] = lbuf[i];
}

// ---------------- selection ----------------

__global__ __launch_bounds__(1024) void k_thresh(const unsigned int* __restrict__ hist,
                                                 unsigned int* __restrict__ Bstar) {
    __shared__ unsigned int sc[1024];
    __shared__ unsigned int part[1024];
    int img = blockIdx.x;
    int t = threadIdx.x;
    const unsigned int* h = hist + ((unsigned)img << 15);
    unsigned psum = 0;
#pragma unroll 4
    for (int i = 0; i < 32; ++i) {
        int bidx = (NBUCK - 1) - (t * 32 + i);
        if (bidx >= 0) psum += h[bidx];
    }
    part[t] = psum;
    sc[t] = psum;
    __syncthreads();
    for (int off = 1; off < 1024; off <<= 1) {
        unsigned add = (t >= off) ? sc[t - off] : 0;
        __syncthreads();
        sc[t] += add;
        __syncthreads();
    }
    unsigned cumBefore = sc[t] - part[t];
    unsigned total = sc[1023];
    if (total < TOPK) {
        if (t == 0) Bstar[img] = 0;
        return;
    }
    if (cumBefore < TOPK && sc[t] >= TOPK) {
        unsigned cum = cumBefore;
        for (int i = 0; i < 32; ++i) {
            int bidx = (NBUCK - 1) - (t * 32 + i);
            unsigned hv = (bidx >= 0) ? h[bidx] : 0;
            if (cum < TOPK && cum + hv >= TOPK) Bstar[img] = (unsigned)bidx;
            cum += hv;
        }
    }
}

__global__ void k_gather(const unsigned long long* __restrict__ cand,
                         const unsigned int* __restrict__ cnt,
                         const unsigned int* __restrict__ Bstar,
                         unsigned long long* __restrict__ gath,
                         unsigned int* __restrict__ gcnt) {
    int img = blockIdx.y;
    unsigned n = cnt[img];
    unsigned Bs = Bstar[img];
    const unsigned long long* c = cand + ((size_t)img << 17);
    unsigned stride = gridDim.x * blockDim.x;
    for (unsigned i = blockIdx.x * blockDim.x + threadIdx.x; i < n; i += stride) {
        unsigned long long key = c[i];
        unsigned bucket = (unsigned)(key >> 47);
        if (bucket >= Bs) {
            unsigned p = atomicAdd(&gcnt[img], 1u);
            if (p < GCAP) gath[((unsigned)img << 13) + p] = key;
        }
    }
}

__global__ __launch_bounds__(1024) void k_sort(const unsigned long long* __restrict__ gath,
                                               const unsigned int* __restrict__ gcnt,
                                               unsigned int* __restrict__ selidx) {
    __shared__ unsigned long long a[GCAP];   // 64 KB
    int img = blockIdx.x;
    int t = threadIdx.x;
    unsigned n = gcnt[img];
    if (n > GCAP) n = GCAP;
    for (int i = t; i < GCAP; i += 1024)
        a[i] = (i < (int)n) ? gath[((unsigned)img << 13) + i] : 0ULL;
    __syncthreads();
    for (int k = 2; k <= GCAP; k <<= 1) {
        for (int j = k >> 1; j > 0; j >>= 1) {
            for (int i = t; i < GCAP; i += 1024) {
                int ij = i ^ j;
                if (ij > i) {
                    unsigned long long x = a[i], y = a[ij];
                    // descending sort
                    bool doswap = ((i & k) == 0) ? (x < y) : (x > y);
                    if (doswap) { a[i] = y; a[ij] = x; }
                }
            }
            __syncthreads();
        }
    }
    for (int k = t; k < TOPK; k += 1024) {
        unsigned long long key = a[k];
        selidx[((unsigned)img << 12) + k] = ~(unsigned)(key & 0xFFFFFFFFULL);
    }
}

// ---------------- finalize: softmax patch + dispersity + bilinear ----------------

__global__ void k_final(const float* __restrict__ S,
                        const unsigned int* __restrict__ selidx,
                        float* __restrict__ out) {
    int t = blockIdx.x * 256 + threadIdx.x;   // 0..32767  (= b*4096 + k)
    int b = t >> 12;
    unsigned rem = selidx[t];
    int row = (int)(rem >> 10);
    int col = (int)(rem & (W - 1));
    const float* Sb = S + ((size_t)b << 20);

    float p[25];
    float mx = -1e30f;
#pragma unroll
    for (int a = 0; a < 5; ++a) {
        int y = row + a - 2;
#pragma unroll
        for (int c2 = 0; c2 < 5; ++c2) {
            int x = col + c2 - 2;
            float v = (y >= 0 && y < H && x >= 0 && x < W) ? Sb[(y << 10) + x] : 0.0f;
            p[a * 5 + c2] = v;
            mx = fmaxf(mx, v);
        }
    }
    float sum = 0.0f, sx = 0.0f, sy = 0.0f;
#pragma unroll
    for (int a = 0; a < 5; ++a) {
#pragma unroll
        for (int c2 = 0; c2 < 5; ++c2) {
            float e = expf((p[a * 5 + c2] - mx) / 0.1f);
            p[a * 5 + c2] = e;
            sum += e;
            sx += e * (float)(c2 - 2);
            sy += e * (float)(a - 2);
        }
    }
    float rx = sx / sum, ry = sy / sum;
    float sd = 0.0f;
#pragma unroll
    for (int a = 0; a < 5; ++a) {
#pragma unroll
        for (int c2 = 0; c2 < 5; ++c2) {
            float dxx = ((float)(c2 - 2) - rx) * 0.5f;
            float dyy = ((float)(a - 2) - ry) * 0.5f;
            sd += p[a * 5 + c2] * (dxx * dxx + dyy * dyy);
        }
    }
    float disp = sd / sum;
    float kx = ((float)col + rx) / (float)(W - 1) * 2.0f - 1.0f;
    float ky = ((float)row + ry) / (float)(H - 1) * 2.0f - 1.0f;

    float px = (kx + 1.0f) * 0.5f * (float)(W - 1);
    float py = (ky + 1.0f) * 0.5f * (float)(H - 1);
    float x0 = floorf(px), y0 = floorf(py);
    float wx1 = px - x0, wx0 = 1.0f - wx1;
    float wy1 = py - y0, wy0 = 1.0f - wy1;

    float g[4];
    float xs[4] = {x0, x0 + 1.0f, x0, x0 + 1.0f};
    float ys[4] = {y0, y0, y0 + 1.0f, y0 + 1.0f};
#pragma unroll
    for (int i = 0; i < 4; ++i) {
        int xi = (int)xs[i]; xi = xi < 0 ? 0 : (xi > W - 1 ? W - 1 : xi);
        int yi = (int)ys[i]; yi = yi < 0 ? 0 : (yi > H - 1 ? H - 1 : yi);
        bool valid = (xs[i] >= 0.0f) && (xs[i] <= (float)(W - 1)) &&
                     (ys[i] >= 0.0f) && (ys[i] <= (float)(H - 1));
        g[i] = valid ? Sb[(yi << 10) + xi] : 0.0f;
    }
    float score = wy0 * wx0 * g[0] + wy0 * wx1 * g[1] + wy1 * wx0 * g[2] + wy1 * wx1 * g[3];

    out[(size_t)t * 2]     = kx;
    out[(size_t)t * 2 + 1] = ky;
    out[B * TOPK * 2 + t]           = disp;
    out[B * TOPK * 2 + B * TOPK + t] = score;
}

// ---------------- launch ----------------

extern "C" void kernel_launch(void* const* d_in, const int* in_sizes, int n_in,
                              void* d_out, int out_size, void* d_ws, size_t ws_size,
                              hipStream_t stream) {
    const float* S = (const float*)d_in[0];
    float* out = (float*)d_out;

    char* w = (char*)d_ws;
    float* ss = (float*)w;                          w += (size_t)B * NPIX * 4;
    unsigned char* m0 = (unsigned char*)w;          w += (size_t)B * NPIX;
    unsigned char* m1 = (unsigned char*)w;          w += (size_t)B * NPIX;
    unsigned char* sp = (unsigned char*)w;          w += (size_t)B * NPIX;
    unsigned long long* cand = (unsigned long long*)w; w += (size_t)B * CANDCAP * 8;
    unsigned long long* gath = (unsigned long long*)w; w += (size_t)B * GCAP * 8;
    unsigned int* selidx = (unsigned int*)w;        w += (size_t)B * TOPK * 4;
    unsigned int* hist = (unsigned int*)w;          w += (size_t)B * HSTRIDE * 4;
    unsigned int* cnt = (unsigned int*)w;           w += B * 4;
    unsigned int* gcnt = (unsigned int*)w;          w += B * 4;
    unsigned int* Bstar = (unsigned int*)w;         w += B * 4;

    // zero hist + cnt + gcnt + Bstar (contiguous)
    hipMemsetAsync(hist, 0, (size_t)B * HSTRIDE * 4 + 3 * B * 4, stream);

    int nblk = (B * NPIX) / 256;   // 32768
    k_m0<<<nblk, 256, 0, stream>>>(S, m0);
    k_dilate_ss<<<nblk, 256, 0, stream>>>(m0, S, sp, ss);
    k_newmask<<<nblk, 256, 0, stream>>>(ss, m0, sp, m1);
    k_dilate_ss<<<nblk, 256, 0, stream>>>(m1, S, sp, ss);
    k_final_nms<<<(B * NPIX) / 2048, 256, 0, stream>>>(S, ss, m1, sp, cand, cnt, hist);
    k_thresh<<<B, 1024, 0, stream>>>(hist, Bstar);
    k_gather<<<dim3(64, B), 256, 0, stream>>>(cand, cnt, Bstar, gath, gcnt);
    k_sort<<<B, 1024, 0, stream>>>(gath, gcnt, selidx);
    k_final<<<(B * TOPK) / 256, 256, 0, stream>>>(S, selidx, out);
}

// Round 2
// 564.948 us; speedup vs baseline: 1.9125x; 1.9125x over previous
//
#include <hip/hip_runtime.h>

#define B 8
#define H 1024
#define W 1024
#define NPIX (H * W)
#define TOPK 4096
#define NBUCK 65537            // bucket 0 = (0,0.5); 1..65536 = 128-ulp bins over [0.5,1)
#define HSTRIDE 65544
#define CANDCAP 131072         // per image
#define GCAP 8192              // gathered per image

#define TS 32                  // output tile
#define HALO 10
#define LT 52                  // loaded tile
#define LTP 53                 // padded float stride
#define MTP 56                 // mask byte stride

__device__ __forceinline__ unsigned val_bucket(unsigned vb) {
    return vb >= 0x3F000000u ? ((vb - 0x3F000000u) >> 7) + 1u : 0u;
}

#define FOR_RECT(Y0, Y1, X0, X1) \
    for (int i = threadIdx.x; i < ((Y1)-(Y0)+1) * ((X1)-(X0)+1); i += 256) { \
        const int _w = (X1)-(X0)+1; \
        int y = (Y0) + i / _w; int x = (X0) + i % _w;
#define END_RECT }

// ---------------- fused 5-pass NMS + candidate compaction + histogram ----------------

__global__ __launch_bounds__(256) void k_nms_fused(const float* __restrict__ S,
                                                   unsigned long long* __restrict__ cand,
                                                   unsigned int* __restrict__ cnt,
                                                   unsigned int* __restrict__ hist) {
    __shared__ float sS[LT][LTP];          // raw scores (-1 outside image)
    __shared__ float sA[LT][LTP];          // row-stage temp
    __shared__ float sB[LT][LTP];          // ss values
    __shared__ unsigned char mM[LT][MTP];  // m0 -> m1 (in place)
    __shared__ unsigned char mT[LT][MTP];  // dilate row temp
    __shared__ unsigned char mS[LT][MTP];  // sp1 -> sp2
    __shared__ unsigned long long lbuf[256];
    __shared__ unsigned int lcnt, lbase;

    int t = threadIdx.x;
    int img = blockIdx.y;
    int tile = blockIdx.x;
    int ty = tile >> 5, tx = tile & 31;
    int gx0 = tx * TS - HALO, gy0 = ty * TS - HALO;
    const float* Sb = S + ((size_t)img << 20);

    if (t == 0) lcnt = 0;

    // load 52x52 (OOB = -1, below every real score)
    for (int i = t; i < LT * LT; i += 256) {
        int y = i / LT, x = i - y * LT;
        int gy = gy0 + y, gx = gx0 + x;
        float v = -1.0f;
        if ((unsigned)gy < H && (unsigned)gx < W) v = Sb[(gy << 10) + gx];
        sS[y][x] = v;
    }
    __syncthreads();

    // P0: m0 = (s == maxpool5(s)) && in-image, valid [2..49]^2
    FOR_RECT(0, 51, 2, 49)
        const float* r = &sS[y][0];
        sA[y][x] = fmaxf(fmaxf(fmaxf(r[x-2], r[x-1]), fmaxf(r[x], r[x+1])), r[x+2]);
    END_RECT
    __syncthreads();
    FOR_RECT(2, 49, 2, 49)
        float mx = fmaxf(fmaxf(fmaxf(sA[y-2][x], sA[y-1][x]),
                               fmaxf(sA[y][x], sA[y+1][x])), sA[y+2][x]);
        int gy = gy0 + y, gx = gx0 + x;
        bool in = ((unsigned)gy < H) && ((unsigned)gx < W);
        mM[y][x] = (in && sS[y][x] == mx) ? 1 : 0;
    END_RECT
    __syncthreads();

    // P1: sp1 = dilate5(m0), ss1 = sp1 ? 0 : s, valid [4..47]^2
    FOR_RECT(2, 49, 4, 47)
        const unsigned char* r = &mM[y][0];
        mT[y][x] = r[x-2] | r[x-1] | r[x] | r[x+1] | r[x+2];
    END_RECT
    __syncthreads();
    FOR_RECT(4, 47, 4, 47)
        unsigned char sp = mT[y-2][x] | mT[y-1][x] | mT[y][x] | mT[y+1][x] | mT[y+2][x];
        mS[y][x] = sp;
        sB[y][x] = sp ? 0.0f : sS[y][x];
    END_RECT
    __syncthreads();

    // P2: new1 = (ss1 == maxpool5(ss1)); m1 = m0 | (new1 & ~sp1), valid [6..45]^2
    FOR_RECT(4, 47, 6, 45)
        const float* r = &sB[y][0];
        sA[y][x] = fmaxf(fmaxf(fmaxf(r[x-2], r[x-1]), fmaxf(r[x], r[x+1])), r[x+2]);
    END_RECT
    __syncthreads();
    FOR_RECT(6, 45, 6, 45)
        float mx = fmaxf(fmaxf(fmaxf(sA[y-2][x], sA[y-1][x]),
                               fmaxf(sA[y][x], sA[y+1][x])), sA[y+2][x]);
        bool nw = (sB[y][x] == mx);
        int gy = gy0 + y, gx = gx0 + x;
        bool in = ((unsigned)gy < H) && ((unsigned)gx < W);
        mM[y][x] = (in && (mM[y][x] || (nw && !mS[y][x]))) ? 1 : 0;
    END_RECT
    __syncthreads();

    // P3: sp2 = dilate5(m1), ss2 = sp2 ? 0 : s, valid [8..43]^2
    FOR_RECT(6, 45, 8, 43)
        const unsigned char* r = &mM[y][0];
        mT[y][x] = r[x-2] | r[x-1] | r[x] | r[x+1] | r[x+2];
    END_RECT
    __syncthreads();
    FOR_RECT(8, 43, 8, 43)
        unsigned char sp = mT[y-2][x] | mT[y-1][x] | mT[y][x] | mT[y+1][x] | mT[y+2][x];
        mS[y][x] = sp;
        sB[y][x] = sp ? 0.0f : sS[y][x];
    END_RECT
    __syncthreads();

    // P4: new2, m2, emit candidates, valid [10..41]^2 (the 32x32 output region)
    FOR_RECT(8, 43, 10, 41)
        const float* r = &sB[y][0];
        sA[y][x] = fmaxf(fmaxf(fmaxf(r[x-2], r[x-1]), fmaxf(r[x], r[x+1])), r[x+2]);
    END_RECT
    __syncthreads();
    FOR_RECT(10, 41, 10, 41)
        float mx = fmaxf(fmaxf(fmaxf(sA[y-2][x], sA[y-1][x]),
                               fmaxf(sA[y][x], sA[y+1][x])), sA[y+2][x]);
        bool nw = (sB[y][x] == mx);
        bool m2 = mM[y][x] || (nw && !mS[y][x]);
        int gy = gy0 + y, gx = gx0 + x;
        float val = m2 ? sS[y][x] : 0.0f;
        if (gy < 2 || gy > H - 3 || gx < 2 || gx > W - 3) val = 0.0f;
        if (val > 0.0f) {
            unsigned vb = __float_as_uint(val);
            atomicAdd(&hist[(unsigned)img * HSTRIDE + val_bucket(vb)], 1u);
            unsigned p = atomicAdd(&lcnt, 1u);
            lbuf[p & 255] = ((unsigned long long)vb << 32) |
                            (unsigned)(~(unsigned)((gy << 10) + gx));
        }
    END_RECT
    __syncthreads();

    if (t == 0) lbase = atomicAdd(&cnt[img], lcnt);
    __syncthreads();
    unsigned n = lcnt;
    for (unsigned i = t; i < n; i += 256)
        cand[((size_t)img << 17) + lbase + i] = lbuf[i];
}

// ---------------- selection ----------------

__global__ __launch_bounds__(1024) void k_thresh(const unsigned int* __restrict__ hist,
                                                 unsigned int* __restrict__ Bstar) {
    __shared__ unsigned int sc[1024];
    __shared__ unsigned int part[1024];
    int img = blockIdx.x;
    int t = threadIdx.x;
    const unsigned int* h = hist + (unsigned)img * HSTRIDE;
    unsigned psum = 0;
    for (int i = 0; i < 65; ++i) {
        int bidx = (NBUCK - 1) - (t * 65 + i);
        if (bidx >= 0) psum += h[bidx];
    }
    part[t] = psum;
    sc[t] = psum;
    __syncthreads();
    for (int off = 1; off < 1024; off <<= 1) {
        unsigned add = (t >= off) ? sc[t - off] : 0;
        __syncthreads();
        sc[t] += add;
        __syncthreads();
    }
    unsigned cumBefore = sc[t] - part[t];
    unsigned total = sc[1023];
    if (total < TOPK) {
        if (t == 0) Bstar[img] = 0;
        return;
    }
    if (cumBefore < TOPK && sc[t] >= TOPK) {
        unsigned cum = cumBefore;
        for (int i = 0; i < 65; ++i) {
            int bidx = (NBUCK - 1) - (t * 65 + i);
            unsigned hv = (bidx >= 0) ? h[bidx] : 0;
            if (cum < TOPK && cum + hv >= TOPK) Bstar[img] = (unsigned)bidx;
            cum += hv;
        }
    }
}

__global__ void k_gather(const unsigned long long* __restrict__ cand,
                         const unsigned int* __restrict__ cnt,
                         const unsigned int* __restrict__ Bstar,
                         unsigned long long* __restrict__ gath,
                         unsigned int* __restrict__ gcnt) {
    int img = blockIdx.y;
    unsigned n = cnt[img];
    unsigned Bs = Bstar[img];
    const unsigned long long* c = cand + ((size_t)img << 17);
    unsigned stride = gridDim.x * blockDim.x;
    for (unsigned i = blockIdx.x * blockDim.x + threadIdx.x; i < n; i += stride) {
        unsigned long long key = c[i];
        unsigned bucket = val_bucket((unsigned)(key >> 32));
        if (bucket >= Bs) {
            unsigned p = atomicAdd(&gcnt[img], 1u);
            if (p < GCAP) gath[((unsigned)img << 13) + p] = key;
        }
    }
}

__global__ __launch_bounds__(1024) void k_sort(const unsigned long long* __restrict__ gath,
                                               const unsigned int* __restrict__ gcnt,
                                               unsigned int* __restrict__ selidx) {
    __shared__ unsigned long long a[GCAP];   // 64 KB
    int img = blockIdx.x;
    int t = threadIdx.x;
    unsigned n = gcnt[img];
    if (n > GCAP) n = GCAP;
    for (int i = t; i < GCAP; i += 1024)
        a[i] = (i < (int)n) ? gath[((unsigned)img << 13) + i] : 0ULL;
    __syncthreads();
    for (int k = 2; k <= GCAP; k <<= 1) {
        for (int j = k >> 1; j > 0; j >>= 1) {
            for (int i = t; i < GCAP; i += 1024) {
                int ij = i ^ j;
                if (ij > i) {
                    unsigned long long x = a[i], y = a[ij];
                    bool doswap = ((i & k) == 0) ? (x < y) : (x > y);   // descending
                    if (doswap) { a[i] = y; a[ij] = x; }
                }
            }
            __syncthreads();
        }
    }
    for (int k = t; k < TOPK; k += 1024) {
        unsigned long long key = a[k];
        selidx[((unsigned)img << 12) + k] = ~(unsigned)(key & 0xFFFFFFFFULL);
    }
}

// ---------------- finalize: softmax patch + dispersity + bilinear ----------------

__global__ void k_final(const float* __restrict__ S,
                        const unsigned int* __restrict__ selidx,
                        float* __restrict__ out) {
    int t = blockIdx.x * 256 + threadIdx.x;   // 0..32767
    int b = t >> 12;
    unsigned rem = selidx[t];
    int row = (int)(rem >> 10);
    int col = (int)(rem & (W - 1));
    const float* Sb = S + ((size_t)b << 20);

    float p[25];
    float mx = -1e30f;
#pragma unroll
    for (int a = 0; a < 5; ++a) {
        int y = row + a - 2;
#pragma unroll
        for (int c2 = 0; c2 < 5; ++c2) {
            int x = col + c2 - 2;
            float v = (y >= 0 && y < H && x >= 0 && x < W) ? Sb[(y << 10) + x] : 0.0f;
            p[a * 5 + c2] = v;
            mx = fmaxf(mx, v);
        }
    }
    float sum = 0.0f, sx = 0.0f, sy = 0.0f;
#pragma unroll
    for (int a = 0; a < 5; ++a) {
#pragma unroll
        for (int c2 = 0; c2 < 5; ++c2) {
            float e = expf((p[a * 5 + c2] - mx) / 0.1f);
            p[a * 5 + c2] = e;
            sum += e;
            sx += e * (float)(c2 - 2);
            sy += e * (float)(a - 2);
        }
    }
    float rx = sx / sum, ry = sy / sum;
    float sd = 0.0f;
#pragma unroll
    for (int a = 0; a < 5; ++a) {
#pragma unroll
        for (int c2 = 0; c2 < 5; ++c2) {
            float dxx = ((float)(c2 - 2) - rx) * 0.5f;
            float dyy = ((float)(a - 2) - ry) * 0.5f;
            sd += p[a * 5 + c2] * (dxx * dxx + dyy * dyy);
        }
    }
    float disp = sd / sum;
    float kx = ((float)col + rx) / (float)(W - 1) * 2.0f - 1.0f;
    float ky = ((float)row + ry) / (float)(H - 1) * 2.0f - 1.0f;

    float px = (kx + 1.0f) * 0.5f * (float)(W - 1);
    float py = (ky + 1.0f) * 0.5f * (float)(H - 1);
    float x0 = floorf(px), y0 = floorf(py);
    float wx1 = px - x0, wx0 = 1.0f - wx1;
    float wy1 = py - y0, wy0 = 1.0f - wy1;

    float g[4];
    float xs[4] = {x0, x0 + 1.0f, x0, x0 + 1.0f};
    float ys[4] = {y0, y0, y0 + 1.0f, y0 + 1.0f};
#pragma unroll
    for (int i = 0; i < 4; ++i) {
        int xi = (int)xs[i]; xi = xi < 0 ? 0 : (xi > W - 1 ? W - 1 : xi);
        int yi = (int)ys[i]; yi = yi < 0 ? 0 : (yi > H - 1 ? H - 1 : yi);
        bool valid = (xs[i] >= 0.0f) && (xs[i] <= (float)(W - 1)) &&
                     (ys[i] >= 0.0f) && (ys[i] <= (float)(H - 1));
        g[i] = valid ? Sb[(yi << 10) + xi] : 0.0f;
    }
    float score = wy0 * wx0 * g[0] + wy0 * wx1 * g[1] + wy1 * wx0 * g[2] + wy1 * wx1 * g[3];

    out[(size_t)t * 2]     = kx;
    out[(size_t)t * 2 + 1] = ky;
    out[B * TOPK * 2 + t]            = disp;
    out[B * TOPK * 2 + B * TOPK + t] = score;
}

// ---------------- launch ----------------

extern "C" void kernel_launch(void* const* d_in, const int* in_sizes, int n_in,
                              void* d_out, int out_size, void* d_ws, size_t ws_size,
                              hipStream_t stream) {
    const float* S = (const float*)d_in[0];
    float* out = (float*)d_out;

    char* w = (char*)d_ws;
    unsigned long long* cand = (unsigned long long*)w; w += (size_t)B * CANDCAP * 8;
    unsigned long long* gath = (unsigned long long*)w; w += (size_t)B * GCAP * 8;
    unsigned int* selidx = (unsigned int*)w;           w += (size_t)B * TOPK * 4;
    unsigned int* hist = (unsigned int*)w;             w += (size_t)B * HSTRIDE * 4;
    unsigned int* cnt = (unsigned int*)w;              w += B * 4;
    unsigned int* gcnt = (unsigned int*)w;             w += B * 4;
    unsigned int* Bstar = (unsigned int*)w;            w += B * 4;

    // zero hist + cnt + gcnt + Bstar (contiguous)
    hipMemsetAsync(hist, 0, (size_t)B * HSTRIDE * 4 + 3 * B * 4, stream);

    k_nms_fused<<<dim3(1024, B), 256, 0, stream>>>(S, cand, cnt, hist);
    k_thresh<<<B, 1024, 0, stream>>>(hist, Bstar);
    k_gather<<<dim3(64, B), 256, 0, stream>>>(cand, cnt, Bstar, gath, gcnt);
    k_sort<<<B, 1024, 0, stream>>>(gath, gcnt, selidx);
    k_final<<<(B * TOPK) / 256, 256, 0, stream>>>(S, selidx, out);
}

// Round 3
// 373.199 us; speedup vs baseline: 2.8952x; 1.5138x over previous
//
#include <hip/hip_runtime.h>

typedef unsigned int u32;
typedef unsigned long long u64;

#define B 8
#define H 1024
#define W 1024
#define TOPK 4096
#define HSTRIDE 8200           // 8193 buckets, padded
#define CANDCAP 131072         // per image
#define GCAP 8192              // gathered per image

#define TS 32                  // output tile
#define LT 52                  // loaded rows
#define STR 64                 // floats (and mask bytes) per LDS row; col c = x_local + 4
#define LBUF 160               // per-tile candidate cap (max possible 121 + tie slack)

__device__ __forceinline__ u32 val_bucket(u32 vb) {
    if (vb < 0x3F000000u) return 0u;
    u32 b = ((vb - 0x3F000000u) >> 10) + 1u;
    return b > 8192u ? 8192u : b;
}

__device__ __forceinline__ float max5(float a, float b, float c, float d, float e) {
    return fmaxf(fmaxf(fmaxf(a, b), fmaxf(c, d)), e);
}

__device__ __forceinline__ u32 shb(u32 hi, u32 lo, int bytes) {
    return (u32)(((((u64)hi) << 32) | lo) >> (8 * bytes));
}

// row max over x-2..x+2 for 4 consecutive cols; src/dst are LDS float arrays
__device__ __forceinline__ void row_pass(const float* src, float* dst,
                                         int g, int ry, int y0, int y1) {
    for (int y = y0 + ry; y <= y1; y += 16) {
        const float* r = src + y * STR + g * 4;
        float4 M = *(const float4*)r;
        float4 L, R;
        L.x = L.y = L.z = L.w = -1e30f;
        R = L;
        if (g > 0)  L = *(const float4*)(r - 4);
        if (g < 15) R = *(const float4*)(r + 4);
        float4 o;
        o.x = max5(L.z, L.w, M.x, M.y, M.z);
        o.y = max5(L.w, M.x, M.y, M.z, M.w);
        o.z = max5(M.x, M.y, M.z, M.w, R.x);
        o.w = max5(M.y, M.z, M.w, R.x, R.y);
        *(float4*)(dst + y * STR + g * 4) = o;
    }
}

__device__ __forceinline__ float4 colmax(const float* src, int y, int g) {
    const float* p = src + y * STR + g * 4;
    float4 a = *(const float4*)(p - 2 * STR);
    float4 b = *(const float4*)(p - STR);
    float4 c = *(const float4*)(p);
    float4 d = *(const float4*)(p + STR);
    float4 e = *(const float4*)(p + 2 * STR);
    float4 o;
    o.x = max5(a.x, b.x, c.x, d.x, e.x);
    o.y = max5(a.y, b.y, c.y, d.y, e.y);
    o.z = max5(a.z, b.z, c.z, d.z, e.z);
    o.w = max5(a.w, b.w, c.w, d.w, e.w);
    return o;
}

// byte-parallel row dilate (OR over x-2..x+2) on mask bytes
__device__ __forceinline__ void mask_row_dilate(const unsigned char* msrc, unsigned char* mdst,
                                                int g, int ry, int y0, int y1) {
    for (int y = y0 + ry; y <= y1; y += 16) {
        const u32* mw = (const u32*)(msrc + y * STR);
        u32 M = mw[g], L = 0, R = 0;
        if (g > 0)  L = mw[g - 1];
        if (g < 15) R = mw[g + 1];
        u32 d = M | shb(M, L, 2) | shb(M, L, 3) | shb(R, M, 1) | shb(R, M, 2);
        ((u32*)(mdst + y * STR))[g] = d;
    }
}

// ---------------- fused 5-pass NMS ----------------

__global__ __launch_bounds__(256) void k_nms(const float* __restrict__ S,
                                             u64* __restrict__ cand,
                                             u32* __restrict__ cnt,
                                             u32* __restrict__ hist) {
    __shared__ float sS[LT * STR];          // raw (-1 at OOB/pads)
    __shared__ float sA[LT * STR];          // rowmax(sS) -> ss1 -> ss2
    __shared__ float sB[LT * STR];          // rowmax temp for ss passes
    __shared__ unsigned char mM[LT * STR];  // m0 -> m1
    __shared__ unsigned char mT[LT * STR];  // dilate row temp
    __shared__ unsigned char mS[LT * STR];  // sp1 -> sp2
    __shared__ u64 lbuf[LBUF];
    __shared__ u32 lcnt, lbase;

    int t = threadIdx.x;
    int g = t & 15, ry = t >> 4;
    int img = blockIdx.y;
    int tile = blockIdx.x;
    int ty = tile >> 5, tx = tile & 31;
    int gy0 = ty * TS - 10;        // gy of array row 0
    int gx0 = tx * TS - 14;        // gx of array col 0
    const float* Sb = S + ((size_t)img << 20);

    if (t == 0) lcnt = 0;

    // load rows 0..51, all 16 groups (64 cols incl pads), OOB = -1
    for (int y = ry; y < LT; y += 16) {
        int gy = gy0 + y;
        bool rin = (unsigned)gy < (unsigned)H;
        float v[4];
#pragma unroll
        for (int i = 0; i < 4; ++i) {
            int gx = gx0 + g * 4 + i;
            v[i] = (rin && (unsigned)gx < (unsigned)W) ? Sb[(gy << 10) + gx] : -1.0f;
        }
        *(float4*)(sS + y * STR + g * 4) = make_float4(v[0], v[1], v[2], v[3]);
    }
    __syncthreads();

    // P0: m0 = (s == maxpool5(s))
    row_pass(sS, sA, g, ry, 0, 51);
    __syncthreads();
    for (int y = 2 + ry; y <= 49; y += 16) {
        float4 mx = colmax(sA, y, g);
        float4 c = *(const float4*)(sS + y * STR + g * 4);
        u32 m = (c.x == mx.x ? 1u : 0u) | (c.y == mx.y ? 0x100u : 0u) |
                (c.z == mx.z ? 0x10000u : 0u) | (c.w == mx.w ? 0x1000000u : 0u);
        ((u32*)(mM + y * STR))[g] = m;
    }
    __syncthreads();

    // P1: sp1 = dilate5(m0); ss1 = sp1 ? 0 : s  -> sA
    mask_row_dilate(mM, mT, g, ry, 2, 49);
    __syncthreads();
    for (int y = 4 + ry; y <= 47; y += 16) {
        const unsigned char* base = mT + y * STR;
        u32 sp = ((const u32*)(base - 2 * STR))[g] | ((const u32*)(base - STR))[g] |
                 ((const u32*)base)[g] | ((const u32*)(base + STR))[g] |
                 ((const u32*)(base + 2 * STR))[g];
        ((u32*)(mS + y * STR))[g] = sp;
        float4 raw = *(const float4*)(sS + y * STR + g * 4);
        float4 ss;
        ss.x = (sp & 0xFFu)       ? 0.0f : raw.x;
        ss.y = (sp & 0xFF00u)     ? 0.0f : raw.y;
        ss.z = (sp & 0xFF0000u)   ? 0.0f : raw.z;
        ss.w = (sp & 0xFF000000u) ? 0.0f : raw.w;
        *(float4*)(sA + y * STR + g * 4) = ss;
    }
    __syncthreads();

    // P2: new1 = (ss1 == maxpool5(ss1)); m1 = m0 | (new1 & ~sp1)
    row_pass(sA, sB, g, ry, 4, 47);
    __syncthreads();
    for (int y = 6 + ry; y <= 45; y += 16) {
        float4 mx = colmax(sB, y, g);
        float4 c = *(const float4*)(sA + y * STR + g * 4);
        u32 old = ((const u32*)(mM + y * STR))[g];
        u32 sp  = ((const u32*)(mS + y * STR))[g];
        u32 nm = 0;
        nm |= ((old & 0xFFu)       || (c.x == mx.x && !(sp & 0xFFu)))       ? 1u : 0u;
        nm |= ((old & 0xFF00u)     || (c.y == mx.y && !(sp & 0xFF00u)))     ? 0x100u : 0u;
        nm |= ((old & 0xFF0000u)   || (c.z == mx.z && !(sp & 0xFF0000u)))   ? 0x10000u : 0u;
        nm |= ((old & 0xFF000000u) || (c.w == mx.w && !(sp & 0xFF000000u))) ? 0x1000000u : 0u;
        ((u32*)(mM + y * STR))[g] = nm;
    }
    __syncthreads();

    // P3: sp2 = dilate5(m1); ss2 = sp2 ? 0 : s  -> sA
    mask_row_dilate(mM, mT, g, ry, 6, 45);
    __syncthreads();
    for (int y = 8 + ry; y <= 43; y += 16) {
        const unsigned char* base = mT + y * STR;
        u32 sp = ((const u32*)(base - 2 * STR))[g] | ((const u32*)(base - STR))[g] |
                 ((const u32*)base)[g] | ((const u32*)(base + STR))[g] |
                 ((const u32*)(base + 2 * STR))[g];
        ((u32*)(mS + y * STR))[g] = sp;
        float4 raw = *(const float4*)(sS + y * STR + g * 4);
        float4 ss;
        ss.x = (sp & 0xFFu)       ? 0.0f : raw.x;
        ss.y = (sp & 0xFF00u)     ? 0.0f : raw.y;
        ss.z = (sp & 0xFF0000u)   ? 0.0f : raw.z;
        ss.w = (sp & 0xFF000000u) ? 0.0f : raw.w;
        *(float4*)(sA + y * STR + g * 4) = ss;
    }
    __syncthreads();

    // P4: new2, m2, emit candidates for output region rows/cols [10..41]
    row_pass(sA, sB, g, ry, 8, 43);
    __syncthreads();
    for (int y = 10 + ry; y <= 41; y += 16) {
        float4 mx = colmax(sB, y, g);
        float4 c = *(const float4*)(sA + y * STR + g * 4);
        float4 raw = *(const float4*)(sS + y * STR + g * 4);
        u32 old = ((const u32*)(mM + y * STR))[g];
        u32 sp  = ((const u32*)(mS + y * STR))[g];
        float cA[4]  = {c.x, c.y, c.z, c.w};
        float mxA[4] = {mx.x, mx.y, mx.z, mx.w};
        float rwA[4] = {raw.x, raw.y, raw.z, raw.w};
        int gy = gy0 + y;
#pragma unroll
        for (int i = 0; i < 4; ++i) {
            int col = g * 4 + i;
            if (col < 14 || col > 45) continue;   // outside this tile's 32x32 output
            bool m2 = ((old >> (8 * i)) & 0xFFu) ||
                      (cA[i] == mxA[i] && !((sp >> (8 * i)) & 0xFFu));
            float val = m2 ? rwA[i] : 0.0f;
            int gx = gx0 + col;
            if (gy < 2 || gy > H - 3 || gx < 2 || gx > W - 3) val = 0.0f;
            if (val > 0.0f) {
                u32 vb = __float_as_uint(val);
                atomicAdd(&hist[(u32)img * HSTRIDE + val_bucket(vb)], 1u);
                u32 p = atomicAdd(&lcnt, 1u);
                if (p < LBUF)
                    lbuf[p] = (((u64)vb) << 32) | (u32)(~(u32)((gy << 10) + gx));
            }
        }
    }
    __syncthreads();

    if (t == 0) lbase = atomicAdd(&cnt[img], lcnt);
    __syncthreads();
    u32 n = lcnt > LBUF ? LBUF : lcnt;
    for (u32 i = t; i < n; i += 256)
        cand[((size_t)img << 17) + lbase + i] = lbuf[i];
}

// ---------------- fused threshold-find + gather ----------------

__global__ __launch_bounds__(1024) void k_select(const u32* __restrict__ hist,
                                                 const u32* __restrict__ cnt,
                                                 const u64* __restrict__ cand,
                                                 u64* __restrict__ gath,
                                                 u32* __restrict__ gcnt) {
    __shared__ u32 sc[1024];
    __shared__ u32 part[1024];
    __shared__ u32 sBstar;
    __shared__ u32 sg;
    int img = blockIdx.x;
    int t = threadIdx.x;
    const u32* h = hist + (u32)img * HSTRIDE;

    u32 loc[8];
    u32 psum = 0;
#pragma unroll
    for (int i = 0; i < 8; ++i) {
        int b = 8192 - (t * 8 + i);          // buckets 8192 .. 1 descending
        loc[i] = h[b];
        psum += loc[i];
    }
    part[t] = psum;
    sc[t] = psum;
    if (t == 0) sg = 0;
    __syncthreads();
    for (int off = 1; off < 1024; off <<= 1) {
        u32 add = (t >= off) ? sc[t - off] : 0;
        __syncthreads();
        sc[t] += add;
        __syncthreads();
    }
    u32 total = sc[1023];
    u32 cumBefore = sc[t] - part[t];
    if (total < TOPK) {
        if (t == 0) sBstar = 0;
    } else if (cumBefore < TOPK && sc[t] >= TOPK) {
        u32 cum = cumBefore;
#pragma unroll
        for (int i = 0; i < 8; ++i) {
            if (cum < TOPK && cum + loc[i] >= TOPK) sBstar = (u32)(8192 - (t * 8 + i));
            cum += loc[i];
        }
    }
    __syncthreads();

    u32 Bs = sBstar;
    u32 n = cnt[img];
    const u64* c = cand + ((size_t)img << 17);
    u32 npad = (n + 1023u) & ~1023u;
    u32 lane = t & 63;
    for (u32 i = t; i < npad; i += 1024) {
        u64 key = 0;
        bool pass = false;
        if (i < n) {
            key = c[i];
            pass = val_bucket((u32)(key >> 32)) >= Bs;
        }
        u64 mball = __ballot(pass);
        if (mball) {
            u32 cw = (u32)__popcll(mball);
            int leader = __ffsll((unsigned long long)mball) - 1;
            u32 wbase = 0;
            if ((int)lane == leader) wbase = atomicAdd(&sg, cw);
            wbase = __shfl(wbase, leader, 64);
            u32 before = (u32)__popcll(mball & ((1ull << lane) - 1ull));
            if (pass && (wbase + before) < GCAP)
                gath[((size_t)img << 13) + wbase + before] = key;
        }
    }
    __syncthreads();
    if (t == 0) gcnt[img] = sg > GCAP ? GCAP : sg;
}

// ---------------- exact order via rank counting ----------------

__global__ __launch_bounds__(256) void k_rank(const u64* __restrict__ gath,
                                              const u32* __restrict__ gcnt,
                                              u32* __restrict__ selidx) {
    __shared__ u64 a[GCAP];   // 64 KB
    int img = blockIdx.y;
    int t = threadIdx.x;
    u32 n = gcnt[img];
    if (n > GCAP) n = GCAP;
    const u64* src = gath + ((size_t)img << 13);
    for (u32 j = t; j < n; j += 256) a[j] = src[j];
    __syncthreads();
    u32 i = blockIdx.x * 256 + t;
    if (i >= n) return;
    u64 key = a[i];
    u32 r = 0;
    u32 j = 0;
    for (; j + 8 <= n; j += 8) {
        r += (a[j] > key)     + (a[j + 1] > key) + (a[j + 2] > key) + (a[j + 3] > key);
        r += (a[j + 4] > key) + (a[j + 5] > key) + (a[j + 6] > key) + (a[j + 7] > key);
    }
    for (; j < n; ++j) r += (a[j] > key);
    if (r < TOPK) selidx[((u32)img << 12) + r] = ~(u32)(key & 0xFFFFFFFFull);
}

// ---------------- finalize: softmax patch + dispersity + bilinear ----------------

__global__ void k_final(const float* __restrict__ S,
                        const u32* __restrict__ selidx,
                        float* __restrict__ out) {
    int t = blockIdx.x * 256 + threadIdx.x;   // 0..32767
    int b = t >> 12;
    u32 rem = selidx[t];
    int row = (int)(rem >> 10);
    int col = (int)(rem & (W - 1));
    const float* Sb = S + ((size_t)b << 20);

    float p[25];
    float mx = -1e30f;
#pragma unroll
    for (int a = 0; a < 5; ++a) {
        int y = row + a - 2;
#pragma unroll
        for (int c2 = 0; c2 < 5; ++c2) {
            int x = col + c2 - 2;
            float v = (y >= 0 && y < H && x >= 0 && x < W) ? Sb[(y << 10) + x] : 0.0f;
            p[a * 5 + c2] = v;
            mx = fmaxf(mx, v);
        }
    }
    float sum = 0.0f, sx = 0.0f, sy = 0.0f;
#pragma unroll
    for (int a = 0; a < 5; ++a) {
#pragma unroll
        for (int c2 = 0; c2 < 5; ++c2) {
            float e = expf((p[a * 5 + c2] - mx) / 0.1f);
            p[a * 5 + c2] = e;
            sum += e;
            sx += e * (float)(c2 - 2);
            sy += e * (float)(a - 2);
        }
    }
    float rx = sx / sum, ry = sy / sum;
    float sd = 0.0f;
#pragma unroll
    for (int a = 0; a < 5; ++a) {
#pragma unroll
        for (int c2 = 0; c2 < 5; ++c2) {
            float dxx = ((float)(c2 - 2) - rx) * 0.5f;
            float dyy = ((float)(a - 2) - ry) * 0.5f;
            sd += p[a * 5 + c2] * (dxx * dxx + dyy * dyy);
        }
    }
    float disp = sd / sum;
    float kx = ((float)col + rx) / (float)(W - 1) * 2.0f - 1.0f;
    float ky = ((float)row + ry) / (float)(H - 1) * 2.0f - 1.0f;

    float px = (kx + 1.0f) * 0.5f * (float)(W - 1);
    float py = (ky + 1.0f) * 0.5f * (float)(H - 1);
    float x0 = floorf(px), y0 = floorf(py);
    float wx1 = px - x0, wx0 = 1.0f - wx1;
    float wy1 = py - y0, wy0 = 1.0f - wy1;

    float gg[4];
    float xs[4] = {x0, x0 + 1.0f, x0, x0 + 1.0f};
    float ys[4] = {y0, y0, y0 + 1.0f, y0 + 1.0f};
#pragma unroll
    for (int i = 0; i < 4; ++i) {
        int xi = (int)xs[i]; xi = xi < 0 ? 0 : (xi > W - 1 ? W - 1 : xi);
        int yi = (int)ys[i]; yi = yi < 0 ? 0 : (yi > H - 1 ? H - 1 : yi);
        bool valid = (xs[i] >= 0.0f) && (xs[i] <= (float)(W - 1)) &&
                     (ys[i] >= 0.0f) && (ys[i] <= (float)(H - 1));
        gg[i] = valid ? Sb[(yi << 10) + xi] : 0.0f;
    }
    float score = wy0 * wx0 * gg[0] + wy0 * wx1 * gg[1] + wy1 * wx0 * gg[2] + wy1 * wx1 * gg[3];

    out[(size_t)t * 2]     = kx;
    out[(size_t)t * 2 + 1] = ky;
    out[B * TOPK * 2 + t]            = disp;
    out[B * TOPK * 2 + B * TOPK + t] = score;
}

// ---------------- launch ----------------

extern "C" void kernel_launch(void* const* d_in, const int* in_sizes, int n_in,
                              void* d_out, int out_size, void* d_ws, size_t ws_size,
                              hipStream_t stream) {
    const float* S = (const float*)d_in[0];
    float* out = (float*)d_out;

    char* w = (char*)d_ws;
    u64* cand = (u64*)w;        w += (size_t)B * CANDCAP * 8;
    u64* gath = (u64*)w;        w += (size_t)B * GCAP * 8;
    u32* selidx = (u32*)w;      w += (size_t)B * TOPK * 4;
    u32* hist = (u32*)w;        w += (size_t)B * HSTRIDE * 4;
    u32* cnt = (u32*)w;         w += B * 4;
    u32* gcnt = (u32*)w;        w += B * 4;

    // zero hist + cnt + gcnt (contiguous)
    hipMemsetAsync(hist, 0, (size_t)B * HSTRIDE * 4 + 2 * B * 4, stream);

    k_nms<<<dim3(1024, B), 256, 0, stream>>>(S, cand, cnt, hist);
    k_select<<<B, 1024, 0, stream>>>(hist, cnt, cand, gath, gcnt);
    k_rank<<<dim3(32, B), 256, 0, stream>>>(gath, gcnt, selidx);
    k_final<<<(B * TOPK) / 256, 256, 0, stream>>>(S, selidx, out);
}

// Round 4
// 345.557 us; speedup vs baseline: 3.1268x; 1.0800x over previous
//
#include <hip/hip_runtime.h>

typedef unsigned int u32;
typedef unsigned long long u64;

#define B 8
#define H 1024
#define W 1024
#define TOPK 4096
#define HSTRIDE 8200           // 8193 buckets, padded
#define CANDCAP 131072         // per image
#define GCAP 8192              // gathered per image
#define LBUFW 640              // per-wave candidate buffer (expect ~225, 2.8x margin)

#define MAX5R(A, j) fmaxf(fmaxf(fmaxf(A[j], A[(j)+1]), fmaxf(A[(j)+2], A[(j)+3])), A[(j)+4])
#define OR5(A, j) (A[j] | A[(j)+1] | A[(j)+2] | A[(j)+3] | A[(j)+4])

__device__ __forceinline__ u32 val_bucket(u32 vb) {
    if (vb < 0x3F000000u) return 0u;
    u32 b = ((vb - 0x3F000000u) >> 10) + 1u;
    return b > 8192u ? 8192u : b;
}

__device__ __forceinline__ float xmax5(float v) {
    float a = fmaxf(v, fmaxf(__shfl_up(v, 1), __shfl_down(v, 1)));
    return fmaxf(a, fmaxf(__shfl_up(v, 2), __shfl_down(v, 2)));
}

__device__ __forceinline__ u64 xdilate(u64 m) {
    return m | (m << 1) | (m >> 1) | (m << 2) | (m >> 2);
}

// ---------------- streaming register-pipeline NMS ----------------
// One wave per 44-col x 64-row output strip. Streams 84 input rows.
// All masks are wave-wide u64 ballots (bit l = lane l = column gx0+l).

__global__ __launch_bounds__(256) void k_nms(const float* __restrict__ S_,
                                             u64* __restrict__ cand,
                                             u32* __restrict__ cnt,
                                             u32* __restrict__ hist) {
    __shared__ u64 lbuf[4][LBUFW];

    int lane = threadIdx.x & 63;
    int wslot = threadIdx.x >> 6;
    int sx = blockIdx.x * 4 + wslot;      // 0..23  (24*44 = 1056 >= 1024)
    int sy = blockIdx.y;                  // 0..15
    int img = blockIdx.z;
    int gx0 = sx * 44 - 10;
    int gy0 = sy * 64;
    int gx = gx0 + lane;
    bool lxok = (unsigned)gx < (unsigned)W;
    const float* Sb = S_ + ((size_t)img << 20);

    u64 validx = __ballot(lxok);
    u64 emask = __ballot(lane >= 10 && lane <= 53 && gx >= 2 && gx <= W - 3);

    // rolling windows. S[k] = s(y0-10+k); R0[k]=r0(y0-4+k); M0[k]=m0(y0-6+k);
    // SP1[k]=sp1(y0-6+k); R1[k]=r1(y0-8+k); M1[k]=m1(y0-10+k);
    // SP2[k]=sp2(y0-10+k); R2[k]=r2(y0-12+k)
    float S[14], R0[8], R1[8], R2[8];
    u64 M0[8], M1[8], SP1[6], SP2[6];
#pragma unroll
    for (int k = 0; k < 14; ++k) S[k] = -1.0f;
#pragma unroll
    for (int k = 0; k < 8; ++k) { R0[k] = -1e30f; R1[k] = -1e30f; R2[k] = -1e30f; M0[k] = 0; M1[k] = 0; }
#pragma unroll
    for (int k = 0; k < 6; ++k) { SP1[k] = 0; SP2[k] = 0; }

    u32 wbase = 0;
    int y0 = gy0 - 10;

    for (int cy = 0; cy < 21; ++cy, y0 += 4) {
        // load 4 input rows
#pragma unroll
        for (int j = 0; j < 4; ++j) {
            int gy = y0 + j;
            float v = -1.0f;
            if ((unsigned)gy < (unsigned)H && lxok) v = Sb[(gy << 10) + gx];
            S[10 + j] = v;
        }
#pragma unroll
        for (int j = 0; j < 4; ++j) {
            // P0: r0(y), m0(y-2)
            R0[4 + j] = xmax5(S[10 + j]);
            float c0 = MAX5R(R0, j);
            u64 m0 = __ballot(S[j + 8] == c0) & validx;
            M0[j + 4] = m0;
            // P1: sp1(y-4) = dilate5x5(m0), ss1(y-4)
            u64 sp1 = xdilate(OR5(M0, j));
            SP1[j + 2] = sp1;
            float ss1 = ((sp1 >> lane) & 1) ? 0.0f : S[j + 6];
            // P2: r1(y-4), new1(y-6), m1(y-6)
            R1[j + 4] = xmax5(ss1);
            float c1 = MAX5R(R1, j);
            float ss1b = ((SP1[j] >> lane) & 1) ? 0.0f : S[j + 4];
            u64 new1 = __ballot(ss1b == c1) & validx;
            u64 m1 = M0[j] | (new1 & ~SP1[j]);
            M1[j + 4] = m1;
            // P3: sp2(y-8), ss2(y-8)
            u64 sp2 = xdilate(OR5(M1, j));
            SP2[j + 2] = sp2;
            float ss2 = ((sp2 >> lane) & 1) ? 0.0f : S[j + 2];
            // P4: r2(y-8), new2(y-10), m2(y-10), emit
            R2[j + 4] = xmax5(ss2);
            if (cy >= 5) {
                float c2 = MAX5R(R2, j);
                float ss2b = ((SP2[j] >> lane) & 1) ? 0.0f : S[j];
                u64 new2 = __ballot(ss2b == c2) & validx;
                u64 m2 = M1[j] | (new2 & ~SP2[j]);
                int gy_out = y0 + j - 10;
                if (gy_out >= 2 && gy_out <= H - 3) {
                    float val = ((m2 >> lane) & 1) ? S[j] : 0.0f;
                    u64 bm = __ballot(val > 0.0f) & emask;
                    if (bm) {
                        u32 cw = (u32)__popcll(bm);
                        u32 prefix = (u32)__popcll(bm & ((1ull << lane) - 1ull));
                        if (((bm >> lane) & 1) && (wbase + prefix) < LBUFW) {
                            u64 key = (((u64)__float_as_uint(val)) << 32) |
                                      (u32)(~(u32)((gy_out << 10) + gx));
                            lbuf[wslot][wbase + prefix] = key;
                        }
                        wbase += cw;
                    }
                }
            }
        }
        // shift windows by 4
#pragma unroll
        for (int k = 0; k < 10; ++k) S[k] = S[k + 4];
#pragma unroll
        for (int k = 0; k < 4; ++k) {
            R0[k] = R0[k + 4]; R1[k] = R1[k + 4]; R2[k] = R2[k + 4];
            M0[k] = M0[k + 4]; M1[k] = M1[k + 4];
        }
#pragma unroll
        for (int k = 0; k < 2; ++k) { SP1[k] = SP1[k + 4]; SP2[k] = SP2[k + 4]; }
    }

    // flush: one global atomic per wave, then burst copy + histogram
    u32 total = wbase > LBUFW ? LBUFW : wbase;
    u32 gbase = 0;
    if (lane == 0) gbase = atomicAdd(&cnt[img], total);
    gbase = (u32)__shfl((int)gbase, 0, 64);
    u64* dst = cand + ((size_t)img << 17);
    u32* hb = hist + (u32)img * HSTRIDE;
    for (u32 i = lane; i < total; i += 64) {
        u64 key = lbuf[wslot][i];
        atomicAdd(&hb[val_bucket((u32)(key >> 32))], 1u);
        dst[gbase + i] = key;
    }
}

// ---------------- threshold bucket ----------------

__global__ __launch_bounds__(1024) void k_thresh(const u32* __restrict__ hist,
                                                 u32* __restrict__ Bstar) {
    __shared__ u32 sc[1024];
    __shared__ u32 part[1024];
    int img = blockIdx.x;
    int t = threadIdx.x;
    const u32* h = hist + (u32)img * HSTRIDE;
    u32 loc[8];
    u32 psum = 0;
#pragma unroll
    for (int i = 0; i < 8; ++i) { loc[i] = h[8192 - (t * 8 + i)]; psum += loc[i]; }
    part[t] = psum;
    sc[t] = psum;
    __syncthreads();
    for (int off = 1; off < 1024; off <<= 1) {
        u32 add = (t >= off) ? sc[t - off] : 0;
        __syncthreads();
        sc[t] += add;
        __syncthreads();
    }
    u32 total = sc[1023];
    u32 cumBefore = sc[t] - part[t];
    if (total < TOPK) {
        if (t == 0) Bstar[img] = 0;
    } else if (cumBefore < TOPK && sc[t] >= TOPK) {
        u32 cum = cumBefore;
#pragma unroll
        for (int i = 0; i < 8; ++i) {
            if (cum < TOPK && cum + loc[i] >= TOPK) Bstar[img] = (u32)(8192 - (t * 8 + i));
            cum += loc[i];
        }
    }
}

// ---------------- gather (parallel, ballot-aggregated atomics) ----------------

__global__ void k_gather(const u64* __restrict__ cand,
                         const u32* __restrict__ cnt,
                         const u32* __restrict__ Bstar,
                         u64* __restrict__ gath,
                         u32* __restrict__ gcnt) {
    int img = blockIdx.y;
    u32 n = cnt[img];
    u32 Bs = Bstar[img];
    const u64* c = cand + ((size_t)img << 17);
    u32 lane = threadIdx.x & 63;
    u32 npad = (n + 8191u) & ~8191u;
    for (u32 i = blockIdx.x * 256 + threadIdx.x; i < npad; i += 8192) {
        bool pass = false;
        u64 key = 0;
        if (i < n) {
            key = c[i];
            pass = val_bucket((u32)(key >> 32)) >= Bs;
        }
        u64 bm = __ballot(pass);
        if (bm) {
            u32 cw = (u32)__popcll(bm);
            int ldr = __ffsll((unsigned long long)bm) - 1;
            u32 wb = 0;
            if ((int)lane == ldr) wb = atomicAdd(&gcnt[img], cw);
            wb = (u32)__shfl((int)wb, ldr, 64);
            u32 before = (u32)__popcll(bm & ((1ull << lane) - 1ull));
            if (pass && wb + before < GCAP)
                gath[((size_t)img << 13) + wb + before] = key;
        }
    }
}

// ---------------- exact order via rank counting ----------------

__global__ __launch_bounds__(256) void k_rank(const u64* __restrict__ gath,
                                              const u32* __restrict__ gcnt,
                                              u32* __restrict__ selidx) {
    __shared__ u64 a[GCAP];   // 64 KB
    int img = blockIdx.y;
    int t = threadIdx.x;
    u32 n = gcnt[img];
    if (n > GCAP) n = GCAP;
    const u64* src = gath + ((size_t)img << 13);
    for (u32 j = t; j < n; j += 256) a[j] = src[j];
    __syncthreads();
    u32 i = blockIdx.x * 256 + t;
    if (i >= n) return;
    u64 key = a[i];
    u32 r = 0;
    u32 j = 0;
    for (; j + 8 <= n; j += 8) {
        r += (a[j] > key)     + (a[j + 1] > key) + (a[j + 2] > key) + (a[j + 3] > key);
        r += (a[j + 4] > key) + (a[j + 5] > key) + (a[j + 6] > key) + (a[j + 7] > key);
    }
    for (; j < n; ++j) r += (a[j] > key);
    if (r < TOPK) selidx[((u32)img << 12) + r] = ~(u32)(key & 0xFFFFFFFFull);
}

// ---------------- finalize: softmax patch + dispersity + bilinear ----------------

__global__ void k_final(const float* __restrict__ S,
                        const u32* __restrict__ selidx,
                        float* __restrict__ out) {
    int t = blockIdx.x * 256 + threadIdx.x;   // 0..32767
    int b = t >> 12;
    u32 rem = selidx[t];
    int row = (int)(rem >> 10);
    int col = (int)(rem & (W - 1));
    const float* Sb = S + ((size_t)b << 20);

    float p[25];
    float mx = -1e30f;
#pragma unroll
    for (int a = 0; a < 5; ++a) {
        int y = row + a - 2;
#pragma unroll
        for (int c2 = 0; c2 < 5; ++c2) {
            int x = col + c2 - 2;
            float v = (y >= 0 && y < H && x >= 0 && x < W) ? Sb[(y << 10) + x] : 0.0f;
            p[a * 5 + c2] = v;
            mx = fmaxf(mx, v);
        }
    }
    float sum = 0.0f, sx = 0.0f, sy = 0.0f;
#pragma unroll
    for (int a = 0; a < 5; ++a) {
#pragma unroll
        for (int c2 = 0; c2 < 5; ++c2) {
            float e = expf((p[a * 5 + c2] - mx) / 0.1f);
            p[a * 5 + c2] = e;
            sum += e;
            sx += e * (float)(c2 - 2);
            sy += e * (float)(a - 2);
        }
    }
    float rx = sx / sum, ry = sy / sum;
    float sd = 0.0f;
#pragma unroll
    for (int a = 0; a < 5; ++a) {
#pragma unroll
        for (int c2 = 0; c2 < 5; ++c2) {
            float dxx = ((float)(c2 - 2) - rx) * 0.5f;
            float dyy = ((float)(a - 2) - ry) * 0.5f;
            sd += p[a * 5 + c2] * (dxx * dxx + dyy * dyy);
        }
    }
    float disp = sd / sum;
    float kx = ((float)col + rx) / (float)(W - 1) * 2.0f - 1.0f;
    float ky = ((float)row + ry) / (float)(H - 1) * 2.0f - 1.0f;

    float px = (kx + 1.0f) * 0.5f * (float)(W - 1);
    float py = (ky + 1.0f) * 0.5f * (float)(H - 1);
    float x0 = floorf(px), y0 = floorf(py);
    float wx1 = px - x0, wx0 = 1.0f - wx1;
    float wy1 = py - y0, wy0 = 1.0f - wy1;

    float gg[4];
    float xs[4] = {x0, x0 + 1.0f, x0, x0 + 1.0f};
    float ys[4] = {y0, y0, y0 + 1.0f, y0 + 1.0f};
#pragma unroll
    for (int i = 0; i < 4; ++i) {
        int xi = (int)xs[i]; xi = xi < 0 ? 0 : (xi > W - 1 ? W - 1 : xi);
        int yi = (int)ys[i]; yi = yi < 0 ? 0 : (yi > H - 1 ? H - 1 : yi);
        bool valid = (xs[i] >= 0.0f) && (xs[i] <= (float)(W - 1)) &&
                     (ys[i] >= 0.0f) && (ys[i] <= (float)(H - 1));
        gg[i] = valid ? Sb[(yi << 10) + xi] : 0.0f;
    }
    float score = wy0 * wx0 * gg[0] + wy0 * wx1 * gg[1] + wy1 * wx0 * gg[2] + wy1 * wx1 * gg[3];

    out[(size_t)t * 2]     = kx;
    out[(size_t)t * 2 + 1] = ky;
    out[B * TOPK * 2 + t]            = disp;
    out[B * TOPK * 2 + B * TOPK + t] = score;
}

// ---------------- launch ----------------

extern "C" void kernel_launch(void* const* d_in, const int* in_sizes, int n_in,
                              void* d_out, int out_size, void* d_ws, size_t ws_size,
                              hipStream_t stream) {
    const float* S = (const float*)d_in[0];
    float* out = (float*)d_out;

    char* w = (char*)d_ws;
    u64* cand = (u64*)w;        w += (size_t)B * CANDCAP * 8;
    u64* gath = (u64*)w;        w += (size_t)B * GCAP * 8;
    u32* selidx = (u32*)w;      w += (size_t)B * TOPK * 4;
    u32* Bstar = (u32*)w;       w += B * 4;
    u32* hist = (u32*)w;        w += (size_t)B * HSTRIDE * 4;
    u32* cnt = (u32*)w;         w += B * 4;
    u32* gcnt = (u32*)w;        w += B * 4;

    // zero hist + cnt + gcnt (contiguous)
    hipMemsetAsync(hist, 0, (size_t)B * HSTRIDE * 4 + 2 * B * 4, stream);

    k_nms<<<dim3(6, 16, B), 256, 0, stream>>>(S, cand, cnt, hist);
    k_thresh<<<B, 1024, 0, stream>>>(hist, Bstar);
    k_gather<<<dim3(32, B), 256, 0, stream>>>(cand, cnt, Bstar, gath, gcnt);
    k_rank<<<dim3(32, B), 256, 0, stream>>>(gath, gcnt, selidx);
    k_final<<<(B * TOPK) / 256, 256, 0, stream>>>(S, selidx, out);
}